// Round 3
// baseline (647.368 us; speedup 1.0000x reference)
//
#include <hip/hip_runtime.h>
#include <math.h>

#define Nn 1024
#define Ee 4
#define Uu 32

// ---------------------------------------------------------------------------
// pre-kernel: grid (128, 5), block 256. blockIdx.y = e (0..3 edge types,
// 4 = residual W2/b2).
//   e<4 : hpre_t[b][e][u][n] = sum_f ann[b,n,f]*Wa[e,f,u] + ba[e,u]  (u-major!)
//   e==4: res[b][n][u]       = sum_f ann[b,n,f]*W2[f,u]  + b2[u]
// ---------------------------------------------------------------------------
template <int F, int FA>
__global__ __launch_bounds__(256) void pre_kernel(
    const float* __restrict__ annA, const float* __restrict__ annB,
    const float* __restrict__ Wa, const float* __restrict__ ba,
    const float* __restrict__ W2, const float* __restrict__ b2,
    float* __restrict__ hpre_t, float* __restrict__ res)
{
    const int e = blockIdx.y;            // 0..4
    __shared__ float wlds[F * Uu];
    __shared__ float blds[Uu];
    const int tid = threadIdx.x;
    const float* wsrc = (e < 4) ? (Wa + (size_t)e * F * Uu) : W2;
    const float* bsrc = (e < 4) ? (ba + (size_t)e * Uu) : b2;
    for (int i = tid; i < F * Uu; i += 256) wlds[i] = wsrc[i];
    if (tid < Uu) blds[tid] = bsrc[tid];
    __syncthreads();

    const int g = blockIdx.x * 256 + tid;   // flat row in [0, B*N)
    const int b = g >> 10;
    const int n = g & 1023;

    float4 a4[F / 4];
    {
        const float4* rA = (const float4*)(annA + (size_t)g * FA);
#pragma unroll
        for (int i = 0; i < FA / 4; ++i) a4[i] = rA[i];
        if constexpr (F > FA) {
            const float4* rB = (const float4*)(annB + (size_t)g * (F - FA));
#pragma unroll
            for (int i = 0; i < (F - FA) / 4; ++i) a4[FA / 4 + i] = rB[i];
        }
    }

    float4 acc[8];
    const float4* bb = (const float4*)blds;
#pragma unroll
    for (int uq = 0; uq < 8; ++uq) acc[uq] = bb[uq];
    const float4* w4 = (const float4*)wlds;
#pragma unroll
    for (int f4 = 0; f4 < F / 4; ++f4) {
        const float4 av = a4[f4];
#pragma unroll
        for (int c = 0; c < 4; ++c) {
            const float s = (c == 0) ? av.x : (c == 1) ? av.y : (c == 2) ? av.z : av.w;
#pragma unroll
            for (int uq = 0; uq < 8; ++uq) {
                const float4 w = w4[(f4 * 4 + c) * 8 + uq];  // uniform -> broadcast
                acc[uq].x = fmaf(s, w.x, acc[uq].x);
                acc[uq].y = fmaf(s, w.y, acc[uq].y);
                acc[uq].z = fmaf(s, w.z, acc[uq].z);
                acc[uq].w = fmaf(s, w.w, acc[uq].w);
            }
        }
    }
    if (e < 4) {
        float* dst = hpre_t + ((size_t)(b * 4 + e) * Uu) * Nn + n;  // [b][e][u][n]
#pragma unroll
        for (int uq = 0; uq < 8; ++uq) {
            dst[(uq * 4 + 0) * Nn] = acc[uq].x;
            dst[(uq * 4 + 1) * Nn] = acc[uq].y;
            dst[(uq * 4 + 2) * Nn] = acc[uq].z;
            dst[(uq * 4 + 3) * Nn] = acc[uq].w;
        }
    } else {
        float4* dst = (float4*)(res + (size_t)g * Uu);
#pragma unroll
        for (int uq = 0; uq < 8; ++uq) dst[uq] = acc[uq];
    }
}

// ---------------------------------------------------------------------------
// main kernel: out[b][n][u] = tanh( sum_e sum_m adj[b,e,n,m]*h_pre[b,e,m,u]
//                                   + res[b,n,u] )
// Depth-2 software pipeline:
//   adj -> registers, 3 rotating buffers (av0/av1/av2), issued 2 iters ahead.
//   h   -> LDS via global_load_lds (16B), 3 rotating 8 KiB buffers.
// Body(t): waitcnt vmcnt(6) [drains iter-t loads, keeps iter-t+1 in flight] ->
//          s_barrier -> issue(t+2) -> compute(t).
// Safe: buf (t+2)%3's last readers (compute t-1) finished before barrier(t).
// ---------------------------------------------------------------------------
__global__ __launch_bounds__(256) void gcn_main_kernel(
    const float* __restrict__ adj,     // [B,E,N,N]
    const float* __restrict__ hpre_t,  // [B,E,U,N]
    const float* __restrict__ res,     // [B,N,U]
    float* __restrict__ out)           // [B,N,U]
{
    __shared__ float hbuf[3][Uu * 64];    // 3 x 8 KiB, [u][m] within chunk

    const int bid = blockIdx.x;                       // 2048 blocks
    const int swz = (bid & 7) * 256 + (bid >> 3);     // XCD-aware, bijective
    const int b = swz >> 6;
    const int n0 = (swz & 63) * 16;
    const int tid = threadIdx.x;
    const int w = tid >> 6;
    const int lane = tid & 63;
    const int gu = lane >> 4;    // u-octet 0..3
    const int ms = lane & 15;    // m-slot 0..15
    const int wrow = n0 + w * 4; // 4 rows per wave

    const float* adjb = adj + (size_t)b * Ee * Nn * Nn;
    const float* hpb  = hpre_t + (size_t)b * Ee * Uu * Nn;
    const int l4 = lane >> 4, l15 = lane & 15;

    float acc[4][8];
#pragma unroll
    for (int r = 0; r < 4; ++r)
#pragma unroll
        for (int j = 0; j < 8; ++j) acc[r][j] = 0.f;

    float4 av0[4], av1[4], av2[4];

    // issue iter T's loads: adj chunk -> AV regs, h chunk -> hbuf[T%3] via glds
#define ISSUE(AV, PH, T)                                                        \
    {                                                                           \
        const int e_ = (T) >> 4, c_ = (T) & 15;                                 \
        const float* ap_ = adjb + ((size_t)(e_ * Nn + wrow)) * Nn + c_ * 64 + ms * 4; \
        AV[0] = *(const float4*)(ap_);                                          \
        AV[1] = *(const float4*)(ap_ + Nn);                                     \
        AV[2] = *(const float4*)(ap_ + 2 * Nn);                                 \
        AV[3] = *(const float4*)(ap_ + 3 * Nn);                                 \
        const float* hs_ = hpb + (size_t)e_ * Uu * Nn + c_ * 64 + l15 * 4;      \
        __builtin_amdgcn_global_load_lds(                                       \
            (const __attribute__((address_space(1))) void*)(hs_ + (size_t)(8 * w + l4) * Nn),     \
            (__attribute__((address_space(3))) void*)(&hbuf[PH][(8 * w) * 64]), 16, 0, 0);        \
        __builtin_amdgcn_global_load_lds(                                       \
            (const __attribute__((address_space(1))) void*)(hs_ + (size_t)(8 * w + 4 + l4) * Nn), \
            (__attribute__((address_space(3))) void*)(&hbuf[PH][(8 * w + 4) * 64]), 16, 0, 0);    \
    }

#define COMPUTE(AV, PH)                                                         \
    {                                                                           \
        _Pragma("unroll")                                                       \
        for (int j = 0; j < 8; ++j) {                                           \
            const float4 hv = *(const float4*)(&hbuf[PH][(gu * 8 + j) * 64 + ms * 4]); \
            _Pragma("unroll")                                                   \
            for (int r = 0; r < 4; ++r) {                                       \
                float t0 = fmaf(AV[r].x, hv.x, acc[r][j]);                      \
                t0 = fmaf(AV[r].y, hv.y, t0);                                   \
                t0 = fmaf(AV[r].z, hv.z, t0);                                   \
                acc[r][j] = fmaf(AV[r].w, hv.w, t0);                            \
            }                                                                   \
        }                                                                       \
    }

#define WAITBAR(N)                                                              \
    {                                                                           \
        __builtin_amdgcn_sched_barrier(0);                                      \
        asm volatile("s_waitcnt vmcnt(" #N ")" ::: "memory");                   \
        __builtin_amdgcn_s_barrier();                                           \
        __builtin_amdgcn_sched_barrier(0);                                      \
    }

    // prologue: iters 0 and 1 in flight (6 loads each)
    ISSUE(av0, 0, 0);
    ISSUE(av1, 1, 1);

    for (int t = 0; t < 60; t += 3) {
        WAITBAR(6); ISSUE(av2, 2, t + 2); COMPUTE(av0, 0);
        WAITBAR(6); ISSUE(av0, 0, t + 3); COMPUTE(av1, 1);
        WAITBAR(6); ISSUE(av1, 1, t + 4); COMPUTE(av2, 2);
    }
    // t = 60 (phase 0): issue 62 -> av2/hbuf[2]
    WAITBAR(6); ISSUE(av2, 2, 62); COMPUTE(av0, 0);
    // t = 61 (phase 1): issue 63 -> av0/hbuf[0]
    WAITBAR(6); ISSUE(av0, 0, 63); COMPUTE(av1, 1);
    // t = 62 (phase 2): no issue
    WAITBAR(6); COMPUTE(av2, 2);
    // t = 63 (phase 0): drain
    WAITBAR(0); COMPUTE(av0, 0);

#undef ISSUE
#undef COMPUTE
#undef WAITBAR

    // reduce partial sums across the 16 m-slot lanes (low 4 lane bits)
#pragma unroll
    for (int r = 0; r < 4; ++r)
#pragma unroll
        for (int j = 0; j < 8; ++j) {
            float v = acc[r][j];
            v += __shfl_xor(v, 1);
            v += __shfl_xor(v, 2);
            v += __shfl_xor(v, 4);
            v += __shfl_xor(v, 8);
            acc[r][j] = v;
        }

    // epilogue: lane ms==r writes row wrow+r
#pragma unroll
    for (int r = 0; r < 4; ++r) {
        if (ms == r) {
            const int n = wrow + r;
            const float* rp = res + ((size_t)b * Nn + n) * Uu + gu * 8;
            float* op = out + ((size_t)b * Nn + n) * Uu + gu * 8;
            const float4 r0 = *(const float4*)(rp);
            const float4 r1 = *(const float4*)(rp + 4);
            float4 o0, o1;
            o0.x = tanhf(acc[r][0] + r0.x);
            o0.y = tanhf(acc[r][1] + r0.y);
            o0.z = tanhf(acc[r][2] + r0.z);
            o0.w = tanhf(acc[r][3] + r0.w);
            o1.x = tanhf(acc[r][4] + r1.x);
            o1.y = tanhf(acc[r][5] + r1.y);
            o1.z = tanhf(acc[r][6] + r1.z);
            o1.w = tanhf(acc[r][7] + r1.w);
            *(float4*)(op) = o0;
            *(float4*)(op + 4) = o1;
        }
    }
}

extern "C" void kernel_launch(void* const* d_in, const int* in_sizes, int n_in,
                              void* d_out, int out_size, void* d_ws, size_t ws_size,
                              hipStream_t stream)
{
    const float* n_tensor = (const float*)d_in[0];  // [32,1024,32]
    const float* adj      = (const float*)d_in[1];  // [32,4,1024,1024]
    const float* W_adj0   = (const float*)d_in[2];  // [4,32,32]
    const float* b_adj0   = (const float*)d_in[3];  // [4,32]
    const float* W2_0     = (const float*)d_in[4];  // [32,32]
    const float* b2_0     = (const float*)d_in[5];  // [32]
    const float* W_adj1   = (const float*)d_in[6];  // [4,64,32]
    const float* b_adj1   = (const float*)d_in[7];  // [4,32]
    const float* W2_1     = (const float*)d_in[8];  // [64,32]
    const float* b2_1     = (const float*)d_in[9];  // [32]
    float* outp = (float*)d_out;

    float* ws   = (float*)d_ws;
    float* hpre = ws;                            // 16 MiB
    float* resb = ws + (size_t)4 * 1024 * 1024;  // 4 MiB
    float* h0   = ws + (size_t)5 * 1024 * 1024;  // 4 MiB

    dim3 pre_grid(128, 5);

    // layer 0 (F = 32)
    pre_kernel<32, 32><<<pre_grid, 256, 0, stream>>>(n_tensor, nullptr, W_adj0, b_adj0,
                                                     W2_0, b2_0, hpre, resb);
    gcn_main_kernel<<<2048, 256, 0, stream>>>(adj, hpre, resb, h0);

    // layer 1 (F = 64, ann = concat(n_tensor, h0))
    pre_kernel<64, 32><<<pre_grid, 256, 0, stream>>>(n_tensor, h0, W_adj1, b_adj1,
                                                     W2_1, b2_1, hpre, resb);
    gcn_main_kernel<<<2048, 256, 0, stream>>>(adj, hpre, resb, outp);
}

// Round 4
// 518.762 us; speedup vs baseline: 1.2479x; 1.2479x over previous
//
#include <hip/hip_runtime.h>
#include <math.h>

#define Nn 1024
#define Ee 4
#define Uu 32

// ---------------------------------------------------------------------------
// pre-kernel: grid (128, 5), block 256. blockIdx.y = e (0..3 edge types,
// 4 = residual W2/b2).
//   e<4 : hpre_t[b][e][u][n] = sum_f ann[b,n,f]*Wa[e,f,u] + ba[e,u]  (u-major!)
//   e==4: res[b][n][u]       = sum_f ann[b,n,f]*W2[f,u]  + b2[u]
// ---------------------------------------------------------------------------
template <int F, int FA>
__global__ __launch_bounds__(256) void pre_kernel(
    const float* __restrict__ annA, const float* __restrict__ annB,
    const float* __restrict__ Wa, const float* __restrict__ ba,
    const float* __restrict__ W2, const float* __restrict__ b2,
    float* __restrict__ hpre_t, float* __restrict__ res)
{
    const int e = blockIdx.y;            // 0..4
    __shared__ float wlds[F * Uu];
    __shared__ float blds[Uu];
    const int tid = threadIdx.x;
    const float* wsrc = (e < 4) ? (Wa + (size_t)e * F * Uu) : W2;
    const float* bsrc = (e < 4) ? (ba + (size_t)e * Uu) : b2;
    for (int i = tid; i < F * Uu; i += 256) wlds[i] = wsrc[i];
    if (tid < Uu) blds[tid] = bsrc[tid];
    __syncthreads();

    const int g = blockIdx.x * 256 + tid;   // flat row in [0, B*N)
    const int b = g >> 10;
    const int n = g & 1023;

    float4 a4[F / 4];
    {
        const float4* rA = (const float4*)(annA + (size_t)g * FA);
#pragma unroll
        for (int i = 0; i < FA / 4; ++i) a4[i] = rA[i];
        if constexpr (F > FA) {
            const float4* rB = (const float4*)(annB + (size_t)g * (F - FA));
#pragma unroll
            for (int i = 0; i < (F - FA) / 4; ++i) a4[FA / 4 + i] = rB[i];
        }
    }

    float4 acc[8];
    const float4* bb = (const float4*)blds;
#pragma unroll
    for (int uq = 0; uq < 8; ++uq) acc[uq] = bb[uq];
    const float4* w4 = (const float4*)wlds;
#pragma unroll
    for (int f4 = 0; f4 < F / 4; ++f4) {
        const float4 av = a4[f4];
#pragma unroll
        for (int c = 0; c < 4; ++c) {
            const float s = (c == 0) ? av.x : (c == 1) ? av.y : (c == 2) ? av.z : av.w;
#pragma unroll
            for (int uq = 0; uq < 8; ++uq) {
                const float4 w = w4[(f4 * 4 + c) * 8 + uq];  // uniform -> broadcast
                acc[uq].x = fmaf(s, w.x, acc[uq].x);
                acc[uq].y = fmaf(s, w.y, acc[uq].y);
                acc[uq].z = fmaf(s, w.z, acc[uq].z);
                acc[uq].w = fmaf(s, w.w, acc[uq].w);
            }
        }
    }
    if (e < 4) {
        float* dst = hpre_t + ((size_t)(b * 4 + e) * Uu) * Nn + n;  // [b][e][u][n]
#pragma unroll
        for (int uq = 0; uq < 8; ++uq) {
            dst[(uq * 4 + 0) * Nn] = acc[uq].x;
            dst[(uq * 4 + 1) * Nn] = acc[uq].y;
            dst[(uq * 4 + 2) * Nn] = acc[uq].z;
            dst[(uq * 4 + 3) * Nn] = acc[uq].w;
        }
    } else {
        float4* dst = (float4*)(res + (size_t)g * Uu);
#pragma unroll
        for (int uq = 0; uq < 8; ++uq) dst[uq] = acc[uq];
    }
}

// ---------------------------------------------------------------------------
// main kernel: out[b][n][u] = tanh( sum_e sum_m adj[b,e,n,m]*h_pre[b,e,m,u]
//                                   + res[b,n,u] )
// BARRIER-FREE main loop. Block tile = 8 rows x 32 u; the m-dimension is
// split across the 4 waves (wave w owns m in [w*256,(w+1)*256) for every e),
// so no data is shared between waves until the tiny epilogue reduce.
// Each wave is an independent global->reg->FMA stream; the compiler pipelines
// loads across chunks with counted vmcnt on its own (no barrier drains).
// Lane = (gu: u-octet 0..3) x (ms: m-subslot 0..15); acc[8 rows][8 u].
// h reads are disjoint per wave (L2-resident, reused by 128 blocks per b);
// adj reads are fully coalesced, read exactly once per layer.
// ---------------------------------------------------------------------------
__global__ __launch_bounds__(256, 2) void gcn_main_kernel(
    const float* __restrict__ adj,     // [B,E,N,N]
    const float* __restrict__ hpre_t,  // [B,E,U,N]
    const float* __restrict__ res,     // [B,N,U]
    float* __restrict__ out)           // [B,N,U]
{
    __shared__ float part[4][8][Uu];   // 4 KB: per-wave partials

    const int bid = blockIdx.x;                       // 4096 blocks
    const int swz = (bid & 7) * 512 + (bid >> 3);     // XCD-aware, bijective
    const int b = swz >> 7;
    const int n0 = (swz & 127) * 8;                   // 8-row tile
    const int tid = threadIdx.x;
    const int w = tid >> 6;
    const int lane = tid & 63;
    const int gu = lane >> 4;    // u-octet 0..3
    const int ms = lane & 15;    // m-subslot 0..15

    const float* adjb = adj + (size_t)b * Ee * Nn * Nn;
    const float* hpb  = hpre_t + (size_t)b * Ee * Uu * Nn;
    const int mbase = w * 256 + ms * 4;   // this wave's m-quarter, lane subslot

    float acc[8][8];
#pragma unroll
    for (int r = 0; r < 8; ++r)
#pragma unroll
        for (int j = 0; j < 8; ++j) acc[r][j] = 0.f;

    // 16 chunks: e = it>>2, 64-m sub-chunk = it&3 (within this wave's quarter)
#pragma unroll 2
    for (int it = 0; it < 16; ++it) {
        const int e = it >> 2, sub = it & 3;
        const float* ap = adjb + ((size_t)e * Nn + n0) * Nn + mbase + sub * 64;
        const float* hp = hpb + ((size_t)e * Uu + gu * 8) * Nn + mbase + sub * 64;
        float4 av[8], hv[8];
#pragma unroll
        for (int r = 0; r < 8; ++r) av[r] = *(const float4*)(ap + (size_t)r * Nn);
#pragma unroll
        for (int j = 0; j < 8; ++j) hv[j] = *(const float4*)(hp + (size_t)j * Nn);
#pragma unroll
        for (int j = 0; j < 8; ++j)
#pragma unroll
            for (int r = 0; r < 8; ++r) {
                float t0 = fmaf(av[r].x, hv[j].x, acc[r][j]);
                t0 = fmaf(av[r].y, hv[j].y, t0);
                t0 = fmaf(av[r].z, hv[j].z, t0);
                acc[r][j] = fmaf(av[r].w, hv[j].w, t0);
            }
    }

    // reduce across the 16 ms lanes (lane bits 0..3)
#pragma unroll
    for (int r = 0; r < 8; ++r)
#pragma unroll
        for (int j = 0; j < 8; ++j) {
            float v = acc[r][j];
            v += __shfl_xor(v, 1);
            v += __shfl_xor(v, 2);
            v += __shfl_xor(v, 4);
            v += __shfl_xor(v, 8);
            acc[r][j] = v;
        }

    // lane ms==r publishes row r's 8 u values for this wave's m-quarter
#pragma unroll
    for (int r = 0; r < 8; ++r) {
        if (ms == r) {
#pragma unroll
            for (int j = 0; j < 8; ++j) part[w][r][gu * 8 + j] = acc[r][j];
        }
    }
    __syncthreads();

    // final: tid -> (row r = tid>>5, u = tid&31); sum 4 wave partials
    {
        const int r = tid >> 5, u = tid & 31;
        const float v = part[0][r][u] + part[1][r][u] + part[2][r][u] + part[3][r][u];
        const size_t oi = ((size_t)b * Nn + n0 + r) * Uu + u;
        out[oi] = tanhf(v + res[oi]);
    }
}

extern "C" void kernel_launch(void* const* d_in, const int* in_sizes, int n_in,
                              void* d_out, int out_size, void* d_ws, size_t ws_size,
                              hipStream_t stream)
{
    const float* n_tensor = (const float*)d_in[0];  // [32,1024,32]
    const float* adj      = (const float*)d_in[1];  // [32,4,1024,1024]
    const float* W_adj0   = (const float*)d_in[2];  // [4,32,32]
    const float* b_adj0   = (const float*)d_in[3];  // [4,32]
    const float* W2_0     = (const float*)d_in[4];  // [32,32]
    const float* b2_0     = (const float*)d_in[5];  // [32]
    const float* W_adj1   = (const float*)d_in[6];  // [4,64,32]
    const float* b_adj1   = (const float*)d_in[7];  // [4,32]
    const float* W2_1     = (const float*)d_in[8];  // [64,32]
    const float* b2_1     = (const float*)d_in[9];  // [32]
    float* outp = (float*)d_out;

    float* ws   = (float*)d_ws;
    float* hpre = ws;                            // 16 MiB
    float* resb = ws + (size_t)4 * 1024 * 1024;  // 4 MiB
    float* h0   = ws + (size_t)5 * 1024 * 1024;  // 4 MiB

    dim3 pre_grid(128, 5);

    // layer 0 (F = 32)
    pre_kernel<32, 32><<<pre_grid, 256, 0, stream>>>(n_tensor, nullptr, W_adj0, b_adj0,
                                                     W2_0, b2_0, hpre, resb);
    gcn_main_kernel<<<4096, 256, 0, stream>>>(adj, hpre, resb, h0);

    // layer 1 (F = 64, ann = concat(n_tensor, h0))
    pre_kernel<64, 32><<<pre_grid, 256, 0, stream>>>(n_tensor, h0, W_adj1, b_adj1,
                                                     W2_1, b2_1, hpre, resb);
    gcn_main_kernel<<<4096, 256, 0, stream>>>(adj, hpre, resb, outp);
}

// Round 5
// 445.192 us; speedup vs baseline: 1.4541x; 1.1653x over previous
//
#include <hip/hip_runtime.h>
#include <math.h>

#define Nn 1024
#define Ee 4
#define Uu 32
#define STAGE_M 512   // m elements staged per (e, half) stage
#define BLOCK_ROWS 32 // 8 waves x 4 rows

// ---------------------------------------------------------------------------
// pre-kernel: grid (128, 5), block 256. blockIdx.y = e (0..3 edge types,
// 4 = residual W2/b2).
//   e<4 : hpre_t[b][e][u][n] = sum_f ann[b,n,f]*Wa[e,f,u] + ba[e,u]  (u-major!)
//   e==4: res[b][n][u]       = sum_f ann[b,n,f]*W2[f,u]  + b2[u]
// ---------------------------------------------------------------------------
template <int F, int FA>
__global__ __launch_bounds__(256) void pre_kernel(
    const float* __restrict__ annA, const float* __restrict__ annB,
    const float* __restrict__ Wa, const float* __restrict__ ba,
    const float* __restrict__ W2, const float* __restrict__ b2,
    float* __restrict__ hpre_t, float* __restrict__ res)
{
    const int e = blockIdx.y;            // 0..4
    __shared__ float wlds[F * Uu];
    __shared__ float blds[Uu];
    const int tid = threadIdx.x;
    const float* wsrc = (e < 4) ? (Wa + (size_t)e * F * Uu) : W2;
    const float* bsrc = (e < 4) ? (ba + (size_t)e * Uu) : b2;
    for (int i = tid; i < F * Uu; i += 256) wlds[i] = wsrc[i];
    if (tid < Uu) blds[tid] = bsrc[tid];
    __syncthreads();

    const int g = blockIdx.x * 256 + tid;   // flat row in [0, B*N)
    const int b = g >> 10;
    const int n = g & 1023;

    float4 a4[F / 4];
    {
        const float4* rA = (const float4*)(annA + (size_t)g * FA);
#pragma unroll
        for (int i = 0; i < FA / 4; ++i) a4[i] = rA[i];
        if constexpr (F > FA) {
            const float4* rB = (const float4*)(annB + (size_t)g * (F - FA));
#pragma unroll
            for (int i = 0; i < (F - FA) / 4; ++i) a4[FA / 4 + i] = rB[i];
        }
    }

    float4 acc[8];
    const float4* bb = (const float4*)blds;
#pragma unroll
    for (int uq = 0; uq < 8; ++uq) acc[uq] = bb[uq];
    const float4* w4 = (const float4*)wlds;
#pragma unroll
    for (int f4 = 0; f4 < F / 4; ++f4) {
        const float4 av = a4[f4];
#pragma unroll
        for (int c = 0; c < 4; ++c) {
            const float s = (c == 0) ? av.x : (c == 1) ? av.y : (c == 2) ? av.z : av.w;
#pragma unroll
            for (int uq = 0; uq < 8; ++uq) {
                const float4 w = w4[(f4 * 4 + c) * 8 + uq];  // uniform -> broadcast
                acc[uq].x = fmaf(s, w.x, acc[uq].x);
                acc[uq].y = fmaf(s, w.y, acc[uq].y);
                acc[uq].z = fmaf(s, w.z, acc[uq].z);
                acc[uq].w = fmaf(s, w.w, acc[uq].w);
            }
        }
    }
    if (e < 4) {
        float* dst = hpre_t + ((size_t)(b * 4 + e) * Uu) * Nn + n;  // [b][e][u][n]
#pragma unroll
        for (int uq = 0; uq < 8; ++uq) {
            dst[(uq * 4 + 0) * Nn] = acc[uq].x;
            dst[(uq * 4 + 1) * Nn] = acc[uq].y;
            dst[(uq * 4 + 2) * Nn] = acc[uq].z;
            dst[(uq * 4 + 3) * Nn] = acc[uq].w;
        }
    } else {
        float4* dst = (float4*)(res + (size_t)g * Uu);
#pragma unroll
        for (int uq = 0; uq < 8; ++uq) dst[uq] = acc[uq];
    }
}

// ---------------------------------------------------------------------------
// main kernel: out[b][n][u] = tanh( sum_e sum_m adj[b,e,n,m]*h_pre[b,e,m,u]
//                                   + res[b,n,u] )
// Stage-structured: 8 stages = (e in 0..3) x (m-half in 0..1). Each stage:
//   [glds-load h tile 32u x 512m (64 KiB) -> barrier]  (vmcnt(0) drain is OK
//    here: it happens only 8x, not per-chunk)
//   [8 chunks of 64 m: adj global->reg float4, h ds_read b128, FMA --
//    BARRIER-FREE stretch, pure register dataflow, compiler software-
//    pipelines the adj stream with counted vmcnt on its own]
// 512 thr = 8 waves x 4 rows; LDS 64 KiB -> 2 blocks/CU (the co-resident
// block's compute covers this block's h-load phase); launch_bounds(512,4)
// caps VGPR at 128 -> 4 waves/SIMD.
// Lane = (gu: u-octet 0..3) x (ms: m-subslot 0..15); acc[4 rows][8 u].
// ---------------------------------------------------------------------------
__global__ __launch_bounds__(512, 4) void gcn_main_kernel(
    const float* __restrict__ adj,     // [B,E,N,N]
    const float* __restrict__ hpre_t,  // [B,E,U,N]
    const float* __restrict__ res,     // [B,N,U]
    float* __restrict__ out)           // [B,N,U]
{
    __shared__ float hlds[Uu * STAGE_M];   // 64 KiB, [u][m] linear (glds needs linear)

    const int bid = blockIdx.x;                       // 1024 blocks
    const int swz = (bid & 7) * 128 + (bid >> 3);     // XCD-aware, bijective
    const int b = swz >> 5;
    const int n0 = (swz & 31) * BLOCK_ROWS;
    const int tid = threadIdx.x;
    const int w = tid >> 6;       // wave 0..7
    const int lane = tid & 63;
    const int gu = lane >> 4;     // u-octet 0..3
    const int ms = lane & 15;     // m-subslot 0..15
    const int wrow = n0 + w * 4;  // 4 rows per wave

    const float* adjb = adj + (size_t)b * Ee * Nn * Nn;
    const float* hpb  = hpre_t + (size_t)b * Ee * Uu * Nn;

    float acc[4][8];
#pragma unroll
    for (int r = 0; r < 4; ++r)
#pragma unroll
        for (int j = 0; j < 8; ++j) acc[r][j] = 0.f;

    for (int s = 0; s < 8; ++s) {
        const int e = s >> 1;
        const int m0 = (s & 1) * STAGE_M;

        // ---- stage load: wave w brings u-rows [w*4, w*4+4) of the h tile ----
        {
            const float* hsrc = hpb + ((size_t)e * Uu + w * 4) * Nn + m0 + lane * 4;
#pragma unroll
            for (int uu = 0; uu < 4; ++uu) {
#pragma unroll
                for (int seg = 0; seg < 2; ++seg) {
                    __builtin_amdgcn_global_load_lds(
                        (const __attribute__((address_space(1))) void*)(hsrc + (size_t)uu * Nn + seg * 256),
                        (__attribute__((address_space(3))) void*)(&hlds[(w * 4 + uu) * STAGE_M + seg * 256]),
                        16, 0, 0);
                }
            }
        }
        __syncthreads();   // one vmcnt(0) drain per stage -- amortized

        // ---- barrier-free compute stretch: 8 chunks of 64 m ----
#pragma unroll
        for (int c = 0; c < 8; ++c) {
            const float* ap = adjb + ((size_t)e * Nn + wrow) * Nn + m0 + c * 64 + ms * 4;
            float4 av[4];
#pragma unroll
            for (int r = 0; r < 4; ++r) av[r] = *(const float4*)(ap + (size_t)r * Nn);
#pragma unroll
            for (int j = 0; j < 8; ++j) {
                const float4 hv = *(const float4*)(&hlds[(gu * 8 + j) * STAGE_M + c * 64 + ms * 4]);
#pragma unroll
                for (int r = 0; r < 4; ++r) {
                    float t0 = fmaf(av[r].x, hv.x, acc[r][j]);
                    t0 = fmaf(av[r].y, hv.y, t0);
                    t0 = fmaf(av[r].z, hv.z, t0);
                    acc[r][j] = fmaf(av[r].w, hv.w, t0);
                }
            }
        }
        __syncthreads();   // last ds_reads done before next stage overwrites hlds
    }

    // reduce partial sums across the 16 ms lanes (lane bits 0..3)
#pragma unroll
    for (int r = 0; r < 4; ++r)
#pragma unroll
        for (int j = 0; j < 8; ++j) {
            float v = acc[r][j];
            v += __shfl_xor(v, 1);
            v += __shfl_xor(v, 2);
            v += __shfl_xor(v, 4);
            v += __shfl_xor(v, 8);
            acc[r][j] = v;
        }

    // epilogue: lane ms==r writes row wrow+r (static acc indexing via unroll)
#pragma unroll
    for (int r = 0; r < 4; ++r) {
        if (ms == r) {
            const int n = wrow + r;
            const float* rp = res + ((size_t)b * Nn + n) * Uu + gu * 8;
            float* op = out + ((size_t)b * Nn + n) * Uu + gu * 8;
            const float4 r0 = *(const float4*)(rp);
            const float4 r1 = *(const float4*)(rp + 4);
            float4 o0, o1;
            o0.x = tanhf(acc[r][0] + r0.x);
            o0.y = tanhf(acc[r][1] + r0.y);
            o0.z = tanhf(acc[r][2] + r0.z);
            o0.w = tanhf(acc[r][3] + r0.w);
            o1.x = tanhf(acc[r][4] + r1.x);
            o1.y = tanhf(acc[r][5] + r1.y);
            o1.z = tanhf(acc[r][6] + r1.z);
            o1.w = tanhf(acc[r][7] + r1.w);
            *(float4*)(op) = o0;
            *(float4*)(op + 4) = o1;
        }
    }
}

extern "C" void kernel_launch(void* const* d_in, const int* in_sizes, int n_in,
                              void* d_out, int out_size, void* d_ws, size_t ws_size,
                              hipStream_t stream)
{
    const float* n_tensor = (const float*)d_in[0];  // [32,1024,32]
    const float* adj      = (const float*)d_in[1];  // [32,4,1024,1024]
    const float* W_adj0   = (const float*)d_in[2];  // [4,32,32]
    const float* b_adj0   = (const float*)d_in[3];  // [4,32]
    const float* W2_0     = (const float*)d_in[4];  // [32,32]
    const float* b2_0     = (const float*)d_in[5];  // [32]
    const float* W_adj1   = (const float*)d_in[6];  // [4,64,32]
    const float* b_adj1   = (const float*)d_in[7];  // [4,32]
    const float* W2_1     = (const float*)d_in[8];  // [64,32]
    const float* b2_1     = (const float*)d_in[9];  // [32]
    float* outp = (float*)d_out;

    float* ws   = (float*)d_ws;
    float* hpre = ws;                            // 16 MiB
    float* resb = ws + (size_t)4 * 1024 * 1024;  // 4 MiB
    float* h0   = ws + (size_t)5 * 1024 * 1024;  // 4 MiB

    dim3 pre_grid(128, 5);

    // layer 0 (F = 32)
    pre_kernel<32, 32><<<pre_grid, 256, 0, stream>>>(n_tensor, nullptr, W_adj0, b_adj0,
                                                     W2_0, b2_0, hpre, resb);
    gcn_main_kernel<<<1024, 512, 0, stream>>>(adj, hpre, resb, h0);

    // layer 1 (F = 64, ann = concat(n_tensor, h0))
    pre_kernel<64, 32><<<pre_grid, 256, 0, stream>>>(n_tensor, h0, W_adj1, b_adj1,
                                                     W2_1, b2_1, hpre, resb);
    gcn_main_kernel<<<1024, 512, 0, stream>>>(adj, hpre, resb, outp);
}